// Round 1
// baseline (434.144 us; speedup 1.0000x reference)
//
#include <hip/hip_runtime.h>
#include <hip/hip_bf16.h>

// LocalWindowedAttention4D on MI355X (gfx950)
// B=2 C=4 S=2048 E=512 H=8 D=64 WIN=256. All-bf16 MFMA pipeline, fp32 accum.
//
// Pipeline: convert fp32->bf16 (inputs+weights) -> 3 proj GEMMs (V written
// transposed [bch*64+d][s]) -> fused windowed attention -> out GEMM (fp32 out).
//
// ws layout (needs 5*16.78MB + 2.1MB ~= 86MB):
//   [0]      Xq bf16      (later reused as ctx)
//   [1*SZ]   Xk bf16      (later reused as vT)
//   [2*SZ]   Xv bf16
//   [3*SZ]   q  bf16
//   [4*SZ]   k  bf16
//   [5*SZ]   Wq,Wk,Wv,Wo bf16 (512KB each)

typedef __bf16 bf16x8 __attribute__((ext_vector_type(8)));
typedef float f32x4 __attribute__((ext_vector_type(4)));
typedef unsigned short u16x8 __attribute__((ext_vector_type(8)));

#define GLDS(gp, lp) __builtin_amdgcn_global_load_lds( \
    (const __attribute__((address_space(1))) void*)(gp), \
    (__attribute__((address_space(3))) void*)(lp), 16, 0, 0)

__device__ __forceinline__ unsigned short f2bf(float f) {
  unsigned u = __float_as_uint(f);
  return (unsigned short)((u + 0x7fffu + ((u >> 16) & 1u)) >> 16);
}

// ---------------- converts ----------------
__global__ void convert_in(const float* __restrict__ s0, const float* __restrict__ s1,
                           const float* __restrict__ s2,
                           unsigned short* __restrict__ d0, unsigned short* __restrict__ d1,
                           unsigned short* __restrict__ d2) {
  const float* s = blockIdx.z == 0 ? s0 : blockIdx.z == 1 ? s1 : s2;
  unsigned short* d = blockIdx.z == 0 ? d0 : blockIdx.z == 1 ? d1 : d2;
  int i = (int)(blockIdx.x * blockDim.x + threadIdx.x) * 8;
  f32x4 a = *reinterpret_cast<const f32x4*>(s + i);
  f32x4 b = *reinterpret_cast<const f32x4*>(s + i + 4);
  u16x8 o;
  o[0] = f2bf(a[0]); o[1] = f2bf(a[1]); o[2] = f2bf(a[2]); o[3] = f2bf(a[3]);
  o[4] = f2bf(b[0]); o[5] = f2bf(b[1]); o[6] = f2bf(b[2]); o[7] = f2bf(b[3]);
  *reinterpret_cast<u16x8*>(d + i) = o;
}

__global__ void convert_w(const float* __restrict__ s0, const float* __restrict__ s1,
                          const float* __restrict__ s2, const float* __restrict__ s3,
                          unsigned short* __restrict__ d0, unsigned short* __restrict__ d1,
                          unsigned short* __restrict__ d2, unsigned short* __restrict__ d3) {
  int z = blockIdx.z;
  const float* s = z == 0 ? s0 : z == 1 ? s1 : z == 2 ? s2 : s3;
  unsigned short* d = z == 0 ? d0 : z == 1 ? d1 : z == 2 ? d2 : d3;
  int i = (int)(blockIdx.x * blockDim.x + threadIdx.x) * 8;
  f32x4 a = *reinterpret_cast<const f32x4*>(s + i);
  f32x4 b = *reinterpret_cast<const f32x4*>(s + i + 4);
  u16x8 o;
  o[0] = f2bf(a[0]); o[1] = f2bf(a[1]); o[2] = f2bf(a[2]); o[3] = f2bf(a[3]);
  o[4] = f2bf(b[0]); o[5] = f2bf(b[1]); o[6] = f2bf(b[2]); o[7] = f2bf(b[3]);
  *reinterpret_cast<u16x8*>(d + i) = o;
}

// ---------------- GEMM: Y[r,e] = sum_k X[r,k]*W[e,k] + bias[e] ----------------
// m97 structure: 128x128 tile, BK=64, 4 waves (2x2 of 64x64), global_load_lds w16.
// M=16384, N=512, K=512 fixed. MODE 0: bf16 row-major out. MODE 1: fp32 out.
// MODE 2: bf16 transposed out vT[(bc*8+h)*64+d][s] via LDS-transpose epilogue.
template<int MODE>
__global__ __launch_bounds__(256, 2)
void gemm_nt(const unsigned short* __restrict__ A, const unsigned short* __restrict__ Bw,
             const float* __restrict__ bias, void* __restrict__ outp) {
  __shared__ char lds_raw[33280];  // staging 2x16KB; MODE2 epilogue 128x130 bf16
  unsigned short* Alds = (unsigned short*)lds_raw;
  unsigned short* Blds = (unsigned short*)(lds_raw + 16384);
  const int t = threadIdx.x;
  const int l = t & 63, w = t >> 6;
  const int lrow = l & 15, lk = l >> 4;
  const int rbase = blockIdx.y * 128, cbase = blockIdx.x * 128;
  const int wm = w >> 1, wn = w & 1;
  f32x4 acc[4][4] = {};

  for (int k0 = 0; k0 < 512; k0 += 64) {
    __syncthreads();
#pragma unroll
    for (int i = 0; i < 4; ++i) {
      int byteoff = w * 4096 + i * 1024;           // wave-uniform LDS dest
      int row = w * 32 + i * 8 + (l >> 3);         // lane's covered row
      int chunk = l & 7;                           // 16B chunk within 128B row
      GLDS(A + (size_t)(rbase + row) * 512 + k0 + chunk * 8, lds_raw + byteoff);
      GLDS(Bw + (size_t)(cbase + row) * 512 + k0 + chunk * 8, lds_raw + 16384 + byteoff);
    }
    __syncthreads();
    bf16x8 af[4][2], bfr[4][2];
#pragma unroll
    for (int mt = 0; mt < 4; ++mt)
#pragma unroll
      for (int ks = 0; ks < 2; ++ks) {
        af[mt][ks]  = *reinterpret_cast<const bf16x8*>(Alds + (wm * 64 + mt * 16 + lrow) * 64 + ks * 32 + lk * 8);
        bfr[mt][ks] = *reinterpret_cast<const bf16x8*>(Blds + (wn * 64 + mt * 16 + lrow) * 64 + ks * 32 + lk * 8);
      }
#pragma unroll
    for (int mt = 0; mt < 4; ++mt)
#pragma unroll
      for (int nt = 0; nt < 4; ++nt) {
        acc[mt][nt] = __builtin_amdgcn_mfma_f32_16x16x32_bf16(af[mt][0], bfr[nt][0], acc[mt][nt], 0, 0, 0);
        acc[mt][nt] = __builtin_amdgcn_mfma_f32_16x16x32_bf16(af[mt][1], bfr[nt][1], acc[mt][nt], 0, 0, 0);
      }
  }

  float bv[4];
#pragma unroll
  for (int nt = 0; nt < 4; ++nt) bv[nt] = bias[cbase + wn * 64 + nt * 16 + lrow];

  if (MODE == 0) {
    unsigned short* out = (unsigned short*)outp;
#pragma unroll
    for (int mt = 0; mt < 4; ++mt)
#pragma unroll
      for (int nt = 0; nt < 4; ++nt)
#pragma unroll
        for (int r = 0; r < 4; ++r) {
          int rg = rbase + wm * 64 + mt * 16 + lk * 4 + r;
          int cg = cbase + wn * 64 + nt * 16 + lrow;
          out[(size_t)rg * 512 + cg] = f2bf(acc[mt][nt][r] + bv[nt]);
        }
  } else if (MODE == 1) {
    float* out = (float*)outp;
#pragma unroll
    for (int mt = 0; mt < 4; ++mt)
#pragma unroll
      for (int nt = 0; nt < 4; ++nt)
#pragma unroll
        for (int r = 0; r < 4; ++r) {
          int rg = rbase + wm * 64 + mt * 16 + lk * 4 + r;
          int cg = cbase + wn * 64 + nt * 16 + lrow;
          out[(size_t)rg * 512 + cg] = acc[mt][nt][r] + bv[nt];
        }
  } else {
    // transpose tile via LDS, store vT[(bc*8+h)*64+d][s] with coalesced 16B rows
    __syncthreads();
    unsigned short* tl = (unsigned short*)lds_raw;  // [128][130] (pad vs bank conflicts)
#pragma unroll
    for (int mt = 0; mt < 4; ++mt)
#pragma unroll
      for (int nt = 0; nt < 4; ++nt)
#pragma unroll
        for (int r = 0; r < 4; ++r)
          tl[(wm * 64 + mt * 16 + lk * 4 + r) * 130 + wn * 64 + nt * 16 + lrow] =
              f2bf(acc[mt][nt][r] + bv[nt]);
    __syncthreads();
    unsigned short* vt = (unsigned short*)outp;
    const int bc = rbase >> 11;
    const int sb = rbase & 2047;
#pragma unroll
    for (int rnd = 0; rnd < 8; ++rnd) {
      int idx = rnd * 256 + t;
      int el = idx >> 4;    // local e col 0..127
      int ch = idx & 15;    // s-chunk of 8
      u16x8 pk;
#pragma unroll
      for (int j2 = 0; j2 < 8; ++j2) pk[j2] = tl[(ch * 8 + j2) * 130 + el];
      int eg = cbase + el;
      int hh = eg >> 6, dd = eg & 63;
      *reinterpret_cast<u16x8*>(vt + ((size_t)(bc * 8 + hh) * 64 + dd) * 2048 + sb + ch * 8) = pk;
    }
  }
}

// ---------------- fused windowed attention ----------------
// grid (j=8, h=8, bc=8), 256 threads = 4 waves x 64 queries.
// Per key-tile (64 keys, 8 tiles = 512 slots): stage K[64][64] + V^T[64][64] in
// LDS (XOR-swizzled via pre-swizzled global source, rule #21), QK^T mfma,
// online softmax (mask ki in [qi+1, qi+256]; j==0 prev-block = zero pad whose
// score-0 entries legitimately enter the softmax denominator), P->LDS, PV mfma.
__global__ __launch_bounds__(256, 2)
void attn_kernel(const unsigned short* __restrict__ qm, const unsigned short* __restrict__ km,
                 const unsigned short* __restrict__ vtm, unsigned short* __restrict__ ctx) {
  __shared__ char lds_raw[49152];  // K 8KB | V^T 8KB | P 4x8KB (per-wave)
  char* Klds = lds_raw;
  char* Vlds = lds_raw + 8192;
  const int t = threadIdx.x, l = t & 63, w = t >> 6;
  char* Plds = lds_raw + 16384 + w * 8192;
  const int j = blockIdx.x, h = blockIdx.y, bc = blockIdx.z;
  const int lrow = l & 15, lk = l >> 4;
  const int qrow0 = bc * 2048 + j * 256 + w * 64;

  bf16x8 qf[4][2];
#pragma unroll
  for (int rt = 0; rt < 4; ++rt)
#pragma unroll
    for (int ks = 0; ks < 2; ++ks)
      qf[rt][ks] = *reinterpret_cast<const bf16x8*>(
          qm + (size_t)(qrow0 + rt * 16 + lrow) * 512 + h * 64 + ks * 32 + lk * 8);

  f32x4 oacc[4][4] = {};
  float ms[4][4], ls[4][4];
#pragma unroll
  for (int rt = 0; rt < 4; ++rt)
#pragma unroll
    for (int r = 0; r < 4; ++r) { ms[rt][r] = -INFINITY; ls[rt][r] = 0.f; }

  for (int tt = 0; tt < 8; ++tt) {
    __syncthreads();
    if (j == 0 && tt < 4) {
      if (tt == 0) {  // zero pad block once (K+V = 16KB)
        f32x4 z = {};
#pragma unroll
        for (int i = 0; i < 4; ++i)
          *reinterpret_cast<f32x4*>(lds_raw + i * 4096 + t * 16) = z;
      }
    } else {
      const int srow0 = bc * 2048 + (j - 1) * 256 + tt * 64;  // key row in [b,c,s]
      const int scol0 = (j - 1) * 256 + tt * 64;              // s-offset for vT
      const int bch = bc * 8 + h;
#pragma unroll
      for (int i = 0; i < 2; ++i) {
        int byteoff = w * 2048 + i * 1024;
        int row = w * 16 + i * 8 + (l >> 3);
        int clog = (l & 7) ^ (row & 7);  // pre-swizzled source chunk
        GLDS(km + (size_t)(srow0 + row) * 512 + h * 64 + clog * 8, Klds + byteoff);
        GLDS(vtm + ((size_t)(bch * 64 + row)) * 2048 + scol0 + clog * 8, Vlds + byteoff);
      }
    }
    __syncthreads();

    // QK^T
    bf16x8 kf[4][2];
#pragma unroll
    for (int kt = 0; kt < 4; ++kt)
#pragma unroll
      for (int ks = 0; ks < 2; ++ks) {
        int row = kt * 16 + lrow;
        int c = ks * 4 + lk;
        kf[kt][ks] = *reinterpret_cast<const bf16x8*>(Klds + row * 128 + ((c ^ (row & 7)) << 4));
      }
    f32x4 sc[4][4];
    f32x4 zero = {};
#pragma unroll
    for (int rt = 0; rt < 4; ++rt)
#pragma unroll
      for (int kt = 0; kt < 4; ++kt) {
        f32x4 s0 = __builtin_amdgcn_mfma_f32_16x16x32_bf16(qf[rt][0], kf[kt][0], zero, 0, 0, 0);
        sc[rt][kt] = __builtin_amdgcn_mfma_f32_16x16x32_bf16(qf[rt][1], kf[kt][1], s0, 0, 0, 0);
      }

    // scale + mask + row-max
    float tmax[4][4];
#pragma unroll
    for (int rt = 0; rt < 4; ++rt)
#pragma unroll
      for (int r = 0; r < 4; ++r) tmax[rt][r] = -INFINITY;
#pragma unroll
    for (int rt = 0; rt < 4; ++rt)
#pragma unroll
      for (int kt = 0; kt < 4; ++kt)
#pragma unroll
        for (int r = 0; r < 4; ++r) {
          int qi = w * 64 + rt * 16 + lk * 4 + r;
          int ki = tt * 64 + kt * 16 + lrow;
          bool ok = (ki > qi) && (ki <= qi + 256);
          float sv = ok ? sc[rt][kt][r] * 0.125f : -1e30f;
          sc[rt][kt][r] = sv;
          tmax[rt][r] = fmaxf(tmax[rt][r], sv);
        }
#pragma unroll
    for (int rt = 0; rt < 4; ++rt)
#pragma unroll
      for (int r = 0; r < 4; ++r) {
#pragma unroll
        for (int dx = 1; dx < 16; dx <<= 1)
          tmax[rt][r] = fmaxf(tmax[rt][r], __shfl_xor(tmax[rt][r], dx, 64));
        float mnew = fmaxf(ms[rt][r], tmax[rt][r]);
        float corr = __expf(ms[rt][r] - mnew);
        ms[rt][r] = mnew;
        ls[rt][r] *= corr;
#pragma unroll
        for (int dt = 0; dt < 4; ++dt) oacc[rt][dt][r] *= corr;
      }

    // P = exp(S-m) -> bf16 -> per-wave LDS (swizzled); row-sum into l
    float psum[4][4] = {};
#pragma unroll
    for (int rt = 0; rt < 4; ++rt)
#pragma unroll
      for (int kt = 0; kt < 4; ++kt)
#pragma unroll
        for (int r = 0; r < 4; ++r) {
          int qi = w * 64 + rt * 16 + lk * 4 + r;
          int ki = tt * 64 + kt * 16 + lrow;
          bool ok = (ki > qi) && (ki <= qi + 256);
          float p = ok ? __expf(sc[rt][kt][r] - ms[rt][r]) : 0.f;
          psum[rt][r] += p;
          int prow = rt * 16 + lk * 4 + r;
          int pcol = kt * 16 + lrow;
          *reinterpret_cast<unsigned short*>(
              Plds + prow * 128 + (((pcol >> 3) ^ (prow & 7)) << 4) + (pcol & 7) * 2) = f2bf(p);
        }
#pragma unroll
    for (int rt = 0; rt < 4; ++rt)
#pragma unroll
      for (int r = 0; r < 4; ++r) {
#pragma unroll
        for (int dx = 1; dx < 16; dx <<= 1)
          psum[rt][r] += __shfl_xor(psum[rt][r], dx, 64);
        ls[rt][r] += psum[rt][r];
      }

    // PV
#pragma unroll
    for (int ks = 0; ks < 2; ++ks) {
      bf16x8 pa[4], vb[4];
#pragma unroll
      for (int rt = 0; rt < 4; ++rt) {
        int row = rt * 16 + lrow;
        int c = ks * 4 + lk;
        pa[rt] = *reinterpret_cast<const bf16x8*>(Plds + row * 128 + ((c ^ (row & 7)) << 4));
      }
#pragma unroll
      for (int dt = 0; dt < 4; ++dt) {
        int row = dt * 16 + lrow;
        int c = ks * 4 + lk;
        vb[dt] = *reinterpret_cast<const bf16x8*>(Vlds + row * 128 + ((c ^ (row & 7)) << 4));
      }
#pragma unroll
      for (int rt = 0; rt < 4; ++rt)
#pragma unroll
        for (int dt = 0; dt < 4; ++dt)
          oacc[rt][dt] = __builtin_amdgcn_mfma_f32_16x16x32_bf16(pa[rt], vb[dt], oacc[rt][dt], 0, 0, 0);
    }
  }

  // normalize + store ctx bf16 [b,c,s,h*64+d]
#pragma unroll
  for (int rt = 0; rt < 4; ++rt)
#pragma unroll
    for (int r = 0; r < 4; ++r) {
      float inv = 1.f / ls[rt][r];
#pragma unroll
      for (int dt = 0; dt < 4; ++dt) {
        int rg = qrow0 + rt * 16 + lk * 4 + r;
        int cg = h * 64 + dt * 16 + lrow;
        ctx[(size_t)rg * 512 + cg] = f2bf(oacc[rt][dt][r] * inv);
      }
    }
}

// ---------------- launch ----------------
extern "C" void kernel_launch(void* const* d_in, const int* in_sizes, int n_in,
                              void* d_out, int out_size, void* d_ws, size_t ws_size,
                              hipStream_t stream) {
  const float* q_in = (const float*)d_in[0];
  const float* k_in = (const float*)d_in[1];
  const float* v_in = (const float*)d_in[2];
  const float* Wq = (const float*)d_in[3];
  const float* bq = (const float*)d_in[4];
  const float* Wk = (const float*)d_in[5];
  const float* bk = (const float*)d_in[6];
  const float* Wv = (const float*)d_in[7];
  const float* bv = (const float*)d_in[8];
  const float* Wo = (const float*)d_in[9];
  const float* bo = (const float*)d_in[10];

  char* ws = (char*)d_ws;
  const size_t SZ = (size_t)16384 * 512 * 2;
  unsigned short* Xq = (unsigned short*)(ws);
  unsigned short* Xk = (unsigned short*)(ws + SZ);
  unsigned short* Xv = (unsigned short*)(ws + 2 * SZ);
  unsigned short* qb = (unsigned short*)(ws + 3 * SZ);
  unsigned short* kb = (unsigned short*)(ws + 4 * SZ);
  unsigned short* wq_b = (unsigned short*)(ws + 5 * SZ);
  unsigned short* wk_b = wq_b + 262144;
  unsigned short* wv_b = wk_b + 262144;
  unsigned short* wo_b = wv_b + 262144;
  unsigned short* vtb = Xk;  // alias: Xk dead after k-GEMM
  unsigned short* ctx = Xq;  // alias: Xq dead after q-GEMM

  convert_in<<<dim3(4096, 1, 3), 256, 0, stream>>>(q_in, k_in, v_in, Xq, Xk, Xv);
  convert_w<<<dim3(128, 1, 4), 256, 0, stream>>>(Wq, Wk, Wv, Wo, wq_b, wk_b, wv_b, wo_b);
  gemm_nt<0><<<dim3(4, 128), 256, 0, stream>>>(Xq, wq_b, bq, qb);
  gemm_nt<0><<<dim3(4, 128), 256, 0, stream>>>(Xk, wk_b, bk, kb);
  gemm_nt<2><<<dim3(4, 128), 256, 0, stream>>>(Xv, wv_b, bv, vtb);
  attn_kernel<<<dim3(8, 8, 8), 256, 0, stream>>>(qb, kb, vtb, ctx);
  gemm_nt<1><<<dim3(4, 128), 256, 0, stream>>>(ctx, wo_b, bo, d_out);
}

// Round 2
// 277.057 us; speedup vs baseline: 1.5670x; 1.5670x over previous
//
#include <hip/hip_runtime.h>
#include <hip/hip_bf16.h>

// LocalWindowedAttention4D on MI355X (gfx950)
// B=2 C=4 S=2048 E=512 H=8 D=64 WIN=256. All-bf16 MFMA pipeline, fp32 accum.
//
// R2: spill-free attention (32 q/wave), absolute-position tile windows with
// analytic zero-pad, double-buffered K/V staging, fused qkv GEMM dispatch.

typedef __bf16 bf16x8 __attribute__((ext_vector_type(8)));
typedef float f32x4 __attribute__((ext_vector_type(4)));
typedef unsigned short u16x8 __attribute__((ext_vector_type(8)));

#define GLDS(gp, lp) __builtin_amdgcn_global_load_lds( \
    (const __attribute__((address_space(1))) void*)(gp), \
    (__attribute__((address_space(3))) void*)(lp), 16, 0, 0)

__device__ __forceinline__ unsigned short f2bf(float f) {
  unsigned u = __float_as_uint(f);
  return (unsigned short)((u + 0x7fffu + ((u >> 16) & 1u)) >> 16);
}

// ---------------- fused convert: 3 inputs (z<3) + 4 weights (z==3) ----------------
__global__ void convert_all(const float* __restrict__ q, const float* __restrict__ k,
                            const float* __restrict__ v,
                            const float* __restrict__ wq, const float* __restrict__ wk,
                            const float* __restrict__ wv, const float* __restrict__ wo,
                            unsigned short* __restrict__ dq, unsigned short* __restrict__ dk,
                            unsigned short* __restrict__ dv,
                            unsigned short* __restrict__ dwq, unsigned short* __restrict__ dwk,
                            unsigned short* __restrict__ dwv, unsigned short* __restrict__ dwo) {
  int z = blockIdx.z;
  const float* s;
  unsigned short* d;
  long long i;
  if (z < 3) {
    s = z == 0 ? q : z == 1 ? k : v;
    d = z == 0 ? dq : z == 1 ? dk : dv;
    i = ((long long)blockIdx.x * 256 + threadIdx.x) * 8;
  } else {
    int x = blockIdx.x;
    if (x >= 512) return;
    int wi = x >> 7;
    s = wi == 0 ? wq : wi == 1 ? wk : wi == 2 ? wv : wo;
    d = wi == 0 ? dwq : wi == 1 ? dwk : wi == 2 ? dwv : dwo;
    i = ((long long)(x & 127) * 256 + threadIdx.x) * 8;
  }
  f32x4 a = *reinterpret_cast<const f32x4*>(s + i);
  f32x4 b = *reinterpret_cast<const f32x4*>(s + i + 4);
  u16x8 o;
  o[0] = f2bf(a[0]); o[1] = f2bf(a[1]); o[2] = f2bf(a[2]); o[3] = f2bf(a[3]);
  o[4] = f2bf(b[0]); o[5] = f2bf(b[1]); o[6] = f2bf(b[2]); o[7] = f2bf(b[3]);
  *reinterpret_cast<u16x8*>(d + i) = o;
}

// ---------------- fused QKV GEMM ----------------
__global__ __launch_bounds__(256, 3)
void gemm_qkv(const unsigned short* __restrict__ Xq, const unsigned short* __restrict__ Xk,
              const unsigned short* __restrict__ Xv,
              const unsigned short* __restrict__ wq, const unsigned short* __restrict__ wk,
              const unsigned short* __restrict__ wv,
              const float* __restrict__ bq, const float* __restrict__ bk,
              const float* __restrict__ bv,
              unsigned short* __restrict__ qout, unsigned short* __restrict__ kout,
              unsigned short* __restrict__ vtout) {
  __shared__ char lds_raw[33280];
  const int z = blockIdx.z;
  const unsigned short* A  = z == 0 ? Xq : z == 1 ? Xk : Xv;
  const unsigned short* Bw = z == 0 ? wq : z == 1 ? wk : wv;
  const float* bias        = z == 0 ? bq : z == 1 ? bk : bv;

  unsigned short* Alds = (unsigned short*)lds_raw;
  unsigned short* Blds = (unsigned short*)(lds_raw + 16384);
  const int t = threadIdx.x;
  const int l = t & 63, w = t >> 6;
  const int lrow = l & 15, lk = l >> 4;
  const int rbase = blockIdx.y * 128, cbase = blockIdx.x * 128;
  const int wm = w >> 1, wn = w & 1;
  f32x4 acc[4][4] = {};

  for (int k0 = 0; k0 < 512; k0 += 64) {
    __syncthreads();
#pragma unroll
    for (int i = 0; i < 4; ++i) {
      int byteoff = w * 4096 + i * 1024;
      int row = w * 32 + i * 8 + (l >> 3);
      int chunk = l & 7;
      GLDS(A + (size_t)(rbase + row) * 512 + k0 + chunk * 8, lds_raw + byteoff);
      GLDS(Bw + (size_t)(cbase + row) * 512 + k0 + chunk * 8, lds_raw + 16384 + byteoff);
    }
    __syncthreads();
    bf16x8 af[4][2], bfr[4][2];
#pragma unroll
    for (int mt = 0; mt < 4; ++mt)
#pragma unroll
      for (int ks = 0; ks < 2; ++ks) {
        af[mt][ks]  = *reinterpret_cast<const bf16x8*>(Alds + (wm * 64 + mt * 16 + lrow) * 64 + ks * 32 + lk * 8);
        bfr[mt][ks] = *reinterpret_cast<const bf16x8*>(Blds + (wn * 64 + mt * 16 + lrow) * 64 + ks * 32 + lk * 8);
      }
#pragma unroll
    for (int mt = 0; mt < 4; ++mt)
#pragma unroll
      for (int nt = 0; nt < 4; ++nt) {
        acc[mt][nt] = __builtin_amdgcn_mfma_f32_16x16x32_bf16(af[mt][0], bfr[nt][0], acc[mt][nt], 0, 0, 0);
        acc[mt][nt] = __builtin_amdgcn_mfma_f32_16x16x32_bf16(af[mt][1], bfr[nt][1], acc[mt][nt], 0, 0, 0);
      }
  }

  float bvv[4];
#pragma unroll
  for (int nt = 0; nt < 4; ++nt) bvv[nt] = bias[cbase + wn * 64 + nt * 16 + lrow];

  if (z < 2) {
    unsigned short* out = z == 0 ? qout : kout;
#pragma unroll
    for (int mt = 0; mt < 4; ++mt)
#pragma unroll
      for (int nt = 0; nt < 4; ++nt)
#pragma unroll
        for (int r = 0; r < 4; ++r) {
          int rg = rbase + wm * 64 + mt * 16 + lk * 4 + r;
          int cg = cbase + wn * 64 + nt * 16 + lrow;
          out[(size_t)rg * 512 + cg] = f2bf(acc[mt][nt][r] + bvv[nt]);
        }
  } else {
    __syncthreads();
    unsigned short* tl = (unsigned short*)lds_raw;  // [128][130]
#pragma unroll
    for (int mt = 0; mt < 4; ++mt)
#pragma unroll
      for (int nt = 0; nt < 4; ++nt)
#pragma unroll
        for (int r = 0; r < 4; ++r)
          tl[(wm * 64 + mt * 16 + lk * 4 + r) * 130 + wn * 64 + nt * 16 + lrow] =
              f2bf(acc[mt][nt][r] + bvv[nt]);
    __syncthreads();
    const int bc = rbase >> 11;
    const int sb = rbase & 2047;
#pragma unroll
    for (int rnd = 0; rnd < 8; ++rnd) {
      int idx = rnd * 256 + t;
      int el = idx >> 4;
      int ch = idx & 15;
      u16x8 pk;
#pragma unroll
      for (int j2 = 0; j2 < 8; ++j2) pk[j2] = tl[(ch * 8 + j2) * 130 + el];
      int eg = cbase + el;
      int hh = eg >> 6, dd = eg & 63;
      *reinterpret_cast<u16x8*>(vtout + ((size_t)(bc * 8 + hh) * 64 + dd) * 2048 + sb + ch * 8) = pk;
    }
  }
}

// ---------------- output GEMM (fp32 out) ----------------
__global__ __launch_bounds__(256, 3)
void gemm_out(const unsigned short* __restrict__ A, const unsigned short* __restrict__ Bw,
              const float* __restrict__ bias, float* __restrict__ out) {
  __shared__ char lds_raw[32768];
  unsigned short* Alds = (unsigned short*)lds_raw;
  unsigned short* Blds = (unsigned short*)(lds_raw + 16384);
  const int t = threadIdx.x;
  const int l = t & 63, w = t >> 6;
  const int lrow = l & 15, lk = l >> 4;
  const int rbase = blockIdx.y * 128, cbase = blockIdx.x * 128;
  const int wm = w >> 1, wn = w & 1;
  f32x4 acc[4][4] = {};

  for (int k0 = 0; k0 < 512; k0 += 64) {
    __syncthreads();
#pragma unroll
    for (int i = 0; i < 4; ++i) {
      int byteoff = w * 4096 + i * 1024;
      int row = w * 32 + i * 8 + (l >> 3);
      int chunk = l & 7;
      GLDS(A + (size_t)(rbase + row) * 512 + k0 + chunk * 8, lds_raw + byteoff);
      GLDS(Bw + (size_t)(cbase + row) * 512 + k0 + chunk * 8, lds_raw + 16384 + byteoff);
    }
    __syncthreads();
    bf16x8 af[4][2], bfr[4][2];
#pragma unroll
    for (int mt = 0; mt < 4; ++mt)
#pragma unroll
      for (int ks = 0; ks < 2; ++ks) {
        af[mt][ks]  = *reinterpret_cast<const bf16x8*>(Alds + (wm * 64 + mt * 16 + lrow) * 64 + ks * 32 + lk * 8);
        bfr[mt][ks] = *reinterpret_cast<const bf16x8*>(Blds + (wn * 64 + mt * 16 + lrow) * 64 + ks * 32 + lk * 8);
      }
#pragma unroll
    for (int mt = 0; mt < 4; ++mt)
#pragma unroll
      for (int nt = 0; nt < 4; ++nt) {
        acc[mt][nt] = __builtin_amdgcn_mfma_f32_16x16x32_bf16(af[mt][0], bfr[nt][0], acc[mt][nt], 0, 0, 0);
        acc[mt][nt] = __builtin_amdgcn_mfma_f32_16x16x32_bf16(af[mt][1], bfr[nt][1], acc[mt][nt], 0, 0, 0);
      }
  }

  float bvv[4];
#pragma unroll
  for (int nt = 0; nt < 4; ++nt) bvv[nt] = bias[cbase + wn * 64 + nt * 16 + lrow];
#pragma unroll
  for (int mt = 0; mt < 4; ++mt)
#pragma unroll
    for (int nt = 0; nt < 4; ++nt)
#pragma unroll
      for (int r = 0; r < 4; ++r) {
        int rg = rbase + wm * 64 + mt * 16 + lk * 4 + r;
        int cg = cbase + wn * 64 + nt * 16 + lrow;
        out[(size_t)rg * 512 + cg] = acc[mt][nt][r] + bvv[nt];
      }
}

// ---------------- fused windowed attention ----------------
__global__ __launch_bounds__(256, 3)
void attn_kernel(const unsigned short* __restrict__ qm, const unsigned short* __restrict__ km,
                 const unsigned short* __restrict__ vtm, unsigned short* __restrict__ ctx) {
  __shared__ char lds_raw[49152];  // 2 x (K 8KB | V 8KB) | P 4 x 4KB
  const int t = threadIdx.x, l = t & 63, w = t >> 6;
  char* Plds = lds_raw + 32768 + w * 4096;
  const int lrow = l & 15, lk = l >> 4;

  int flat = blockIdx.x + 16 * (blockIdx.y + 8 * blockIdx.z);
  int swz = (flat & 7) * 128 + (flat >> 3);   // nwg=1024, bijective XCD swizzle
  const int jh = swz & 15, h = (swz >> 4) & 7, bc = swz >> 7;

  const int Qb = jh * 128;
  const int qlo = Qb + w * 32;
  const int h64 = h * 64;
  const size_t bcrow = (size_t)bc * 2048;
  const size_t bch64 = ((size_t)(bc * 8 + h)) * 64;

  const int tlo = (Qb > 255 ? Qb - 255 : 0) >> 6;
  const int thi = (Qb + 127) >> 6;
  const int nt = thi - tlo + 1;                 // 2, 4 or 6
  const int wlo = (qlo > 255 ? qlo - 255 : 0) >> 6;
  const int whi = (qlo + 31) >> 6;

  auto stage = [&](int tt, int buf) {
    char* Kb = lds_raw + buf * 16384;
#pragma unroll
    for (int i = 0; i < 2; ++i) {
      int byteoff = w * 2048 + i * 1024;
      int row = w * 16 + i * 8 + (l >> 3);
      int clog = (l & 7) ^ (row & 7);
      GLDS(km + (bcrow + tt * 64 + row) * 512 + h64 + clog * 8, Kb + byteoff);
      GLDS(vtm + (bch64 + row) * 2048 + tt * 64 + clog * 8, Kb + 8192 + byteoff);
    }
  };

  bf16x8 qf[2][2];
#pragma unroll
  for (int rt = 0; rt < 2; ++rt)
#pragma unroll
    for (int ks = 0; ks < 2; ++ks)
      qf[rt][ks] = *reinterpret_cast<const bf16x8*>(
          qm + (bcrow + qlo + rt * 16 + lrow) * 512 + h64 + ks * 32 + lk * 8);

  f32x4 oacc[2][4] = {};
  float ms[2][4], ls[2][4];
#pragma unroll
  for (int rt = 0; rt < 2; ++rt)
#pragma unroll
    for (int r = 0; r < 4; ++r) { ms[rt][r] = -INFINITY; ls[rt][r] = 0.f; }

  stage(tlo, 0);
  __syncthreads();

  for (int it = 0; it < nt; ++it) {
    const int tt = tlo + it;
    if (it + 1 < nt) stage(tt + 1, (it + 1) & 1);

    if (tt >= wlo && tt <= whi) {
      char* Kb = lds_raw + (it & 1) * 16384;
      char* Vb = Kb + 8192;

      // QK^T
      f32x4 sc[2][4];
      f32x4 zero = {};
#pragma unroll
      for (int kt = 0; kt < 4; ++kt) {
        int krow = kt * 16 + lrow;
        const char* kbase = Kb + krow * 128;
        bf16x8 kf0 = *reinterpret_cast<const bf16x8*>(kbase + ((lk ^ (krow & 7)) << 4));
        bf16x8 kf1 = *reinterpret_cast<const bf16x8*>(kbase + (((4 + lk) ^ (krow & 7)) << 4));
#pragma unroll
        for (int rt = 0; rt < 2; ++rt) {
          f32x4 s0 = __builtin_amdgcn_mfma_f32_16x16x32_bf16(qf[rt][0], kf0, zero, 0, 0, 0);
          sc[rt][kt] = __builtin_amdgcn_mfma_f32_16x16x32_bf16(qf[rt][1], kf1, s0, 0, 0, 0);
        }
      }

      // scale + mask + row-max
      float tmax[2][4];
#pragma unroll
      for (int rt = 0; rt < 2; ++rt)
#pragma unroll
        for (int r = 0; r < 4; ++r) tmax[rt][r] = -1e30f;
#pragma unroll
      for (int rt = 0; rt < 2; ++rt)
#pragma unroll
        for (int kt = 0; kt < 4; ++kt)
#pragma unroll
          for (int r = 0; r < 4; ++r) {
            int p = qlo + rt * 16 + lk * 4 + r;
            int kk = tt * 64 + kt * 16 + lrow;
            bool ok = (kk <= p) && (kk + 255 >= p);
            float sv = ok ? sc[rt][kt][r] * 0.125f : -1e30f;
            sc[rt][kt][r] = sv;
            tmax[rt][r] = fmaxf(tmax[rt][r], sv);
          }
#pragma unroll
      for (int rt = 0; rt < 2; ++rt)
#pragma unroll
        for (int r = 0; r < 4; ++r) {
#pragma unroll
          for (int dx = 1; dx < 16; dx <<= 1)
            tmax[rt][r] = fmaxf(tmax[rt][r], __shfl_xor(tmax[rt][r], dx, 64));
          float mnew = fmaxf(ms[rt][r], tmax[rt][r]);
          float corr = __expf(ms[rt][r] - mnew);
          ms[rt][r] = mnew;
          ls[rt][r] *= corr;
#pragma unroll
          for (int dt = 0; dt < 4; ++dt) oacc[rt][dt][r] *= corr;
        }

      // P = exp(S-m) -> bf16 -> per-wave LDS (swizzled); row-sum
      float psum[2][4] = {};
#pragma unroll
      for (int rt = 0; rt < 2; ++rt)
#pragma unroll
        for (int kt = 0; kt < 4; ++kt)
#pragma unroll
          for (int r = 0; r < 4; ++r) {
            int p_ = qlo + rt * 16 + lk * 4 + r;
            int kk = tt * 64 + kt * 16 + lrow;
            bool ok = (kk <= p_) && (kk + 255 >= p_);
            float pv = ok ? __expf(sc[rt][kt][r] - ms[rt][r]) : 0.f;
            psum[rt][r] += pv;
            int prow = rt * 16 + lk * 4 + r;
            int pcol = kt * 16 + lrow;
            *reinterpret_cast<unsigned short*>(
                Plds + prow * 128 + (((pcol >> 3) ^ (prow & 7)) << 4) + (pcol & 7) * 2) = f2bf(pv);
          }
#pragma unroll
      for (int rt = 0; rt < 2; ++rt)
#pragma unroll
        for (int r = 0; r < 4; ++r) {
#pragma unroll
          for (int dx = 1; dx < 16; dx <<= 1)
            psum[rt][r] += __shfl_xor(psum[rt][r], dx, 64);
          ls[rt][r] += psum[rt][r];
        }

      // PV
#pragma unroll
      for (int ks = 0; ks < 2; ++ks) {
        bf16x8 pa[2], vb[4];
#pragma unroll
        for (int rt = 0; rt < 2; ++rt) {
          int row = rt * 16 + lrow;
          int c = ks * 4 + lk;
          pa[rt] = *reinterpret_cast<const bf16x8*>(Plds + row * 128 + ((c ^ (row & 7)) << 4));
        }
#pragma unroll
        for (int dt = 0; dt < 4; ++dt) {
          int row = dt * 16 + lrow;
          int c = ks * 4 + lk;
          vb[dt] = *reinterpret_cast<const bf16x8*>(Vb + row * 128 + ((c ^ (row & 7)) << 4));
        }
#pragma unroll
        for (int rt = 0; rt < 2; ++rt)
#pragma unroll
          for (int dt = 0; dt < 4; ++dt)
            oacc[rt][dt] = __builtin_amdgcn_mfma_f32_16x16x32_bf16(pa[rt], vb[dt], oacc[rt][dt], 0, 0, 0);
      }
    }
    __syncthreads();
  }

  // analytic zero-pad for p < 255
  if (qlo < 255) {
#pragma unroll
    for (int rt = 0; rt < 2; ++rt)
#pragma unroll
      for (int r = 0; r < 4; ++r) {
        int p = qlo + rt * 16 + lk * 4 + r;
        float cp = (float)(255 - p > 0 ? 255 - p : 0);
        float m = ms[rt][r];
        float mn = cp > 0.f ? fmaxf(m, 0.f) : m;
        float sc0 = __expf(m - mn);
        ls[rt][r] = ls[rt][r] * sc0 + cp * __expf(-mn);
#pragma unroll
        for (int dt = 0; dt < 4; ++dt) oacc[rt][dt][r] *= sc0;
      }
  }

  // normalize + store
#pragma unroll
  for (int rt = 0; rt < 2; ++rt)
#pragma unroll
    for (int r = 0; r < 4; ++r) {
      float inv = 1.f / ls[rt][r];
#pragma unroll
      for (int dt = 0; dt < 4; ++dt) {
        size_t rg = bcrow + qlo + rt * 16 + lk * 4 + r;
        int cg = h64 + dt * 16 + lrow;
        ctx[rg * 512 + cg] = f2bf(oacc[rt][dt][r] * inv);
      }
    }
}

// ---------------- launch ----------------
extern "C" void kernel_launch(void* const* d_in, const int* in_sizes, int n_in,
                              void* d_out, int out_size, void* d_ws, size_t ws_size,
                              hipStream_t stream) {
  const float* q_in = (const float*)d_in[0];
  const float* k_in = (const float*)d_in[1];
  const float* v_in = (const float*)d_in[2];
  const float* Wq = (const float*)d_in[3];
  const float* bq = (const float*)d_in[4];
  const float* Wk = (const float*)d_in[5];
  const float* bk = (const float*)d_in[6];
  const float* Wv = (const float*)d_in[7];
  const float* bv = (const float*)d_in[8];
  const float* Wo = (const float*)d_in[9];
  const float* bo = (const float*)d_in[10];

  char* ws = (char*)d_ws;
  const size_t SZ = (size_t)16384 * 512 * 2;
  unsigned short* Xq = (unsigned short*)(ws);
  unsigned short* Xk = (unsigned short*)(ws + SZ);
  unsigned short* Xv = (unsigned short*)(ws + 2 * SZ);
  unsigned short* qb = (unsigned short*)(ws + 3 * SZ);
  unsigned short* kb = (unsigned short*)(ws + 4 * SZ);
  unsigned short* wq_b = (unsigned short*)(ws + 5 * SZ);
  unsigned short* wk_b = wq_b + 262144;
  unsigned short* wv_b = wk_b + 262144;
  unsigned short* wo_b = wv_b + 262144;
  unsigned short* vtb = (unsigned short*)d_out;  // vT in d_out (dead before gemm_out)
  unsigned short* ctx = Xq;                      // Xq dead after q-GEMM

  convert_all<<<dim3(4096, 1, 4), 256, 0, stream>>>(q_in, k_in, v_in, Wq, Wk, Wv, Wo,
                                                    Xq, Xk, Xv, wq_b, wk_b, wv_b, wo_b);
  gemm_qkv<<<dim3(4, 128, 3), 256, 0, stream>>>(Xq, Xk, Xv, wq_b, wk_b, wv_b,
                                                bq, bk, bv, qb, kb, vtb);
  attn_kernel<<<dim3(16, 8, 8), 256, 0, stream>>>(qb, kb, vtb, ctx);
  gemm_out<<<dim3(4, 128), 256, 0, stream>>>(ctx, wo_b, bo, (float*)d_out);
}

// Round 3
// 250.232 us; speedup vs baseline: 1.7350x; 1.1072x over previous
//
#include <hip/hip_runtime.h>
#include <hip/hip_bf16.h>

// LocalWindowedAttention4D on MI355X (gfx950)
// B=2 C=4 S=2048 E=512 H=8 D=64 WIN=256. All-bf16 MFMA pipeline, fp32 accum.
//
// R3: attention redesign — swapped QK^T (mfma(K,Q): lane-local score rows),
// no-max softmax (scores bounded -> exp(S)/sum directly; pad = +1/elem),
// packed P (cvt_pk + ds_write_b64, 2KB/wave halves), 40KB LDS -> 4 wgs/CU.

typedef __bf16 bf16x8 __attribute__((ext_vector_type(8)));
typedef float f32x4 __attribute__((ext_vector_type(4)));
typedef unsigned short u16x8 __attribute__((ext_vector_type(8)));
typedef unsigned int u32x2 __attribute__((ext_vector_type(2)));

#define GLDS(gp, lp) __builtin_amdgcn_global_load_lds( \
    (const __attribute__((address_space(1))) void*)(gp), \
    (__attribute__((address_space(3))) void*)(lp), 16, 0, 0)

__device__ __forceinline__ unsigned short f2bf(float f) {
  unsigned u = __float_as_uint(f);
  return (unsigned short)((u + 0x7fffu + ((u >> 16) & 1u)) >> 16);
}

// ---------------- fused convert: 3 inputs (z<3) + 4 weights (z==3) ----------------
__global__ void convert_all(const float* __restrict__ q, const float* __restrict__ k,
                            const float* __restrict__ v,
                            const float* __restrict__ wq, const float* __restrict__ wk,
                            const float* __restrict__ wv, const float* __restrict__ wo,
                            unsigned short* __restrict__ dq, unsigned short* __restrict__ dk,
                            unsigned short* __restrict__ dv,
                            unsigned short* __restrict__ dwq, unsigned short* __restrict__ dwk,
                            unsigned short* __restrict__ dwv, unsigned short* __restrict__ dwo) {
  int z = blockIdx.z;
  const float* s;
  unsigned short* d;
  long long i;
  if (z < 3) {
    s = z == 0 ? q : z == 1 ? k : v;
    d = z == 0 ? dq : z == 1 ? dk : dv;
    i = ((long long)blockIdx.x * 256 + threadIdx.x) * 8;
  } else {
    int x = blockIdx.x;
    if (x >= 512) return;
    int wi = x >> 7;
    s = wi == 0 ? wq : wi == 1 ? wk : wi == 2 ? wv : wo;
    d = wi == 0 ? dwq : wi == 1 ? dwk : wi == 2 ? dwv : dwo;
    i = ((long long)(x & 127) * 256 + threadIdx.x) * 8;
  }
  f32x4 a = *reinterpret_cast<const f32x4*>(s + i);
  f32x4 b = *reinterpret_cast<const f32x4*>(s + i + 4);
  u16x8 o;
  o[0] = f2bf(a[0]); o[1] = f2bf(a[1]); o[2] = f2bf(a[2]); o[3] = f2bf(a[3]);
  o[4] = f2bf(b[0]); o[5] = f2bf(b[1]); o[6] = f2bf(b[2]); o[7] = f2bf(b[3]);
  *reinterpret_cast<u16x8*>(d + i) = o;
}

// ---------------- fused QKV GEMM ----------------
__global__ __launch_bounds__(256, 3)
void gemm_qkv(const unsigned short* __restrict__ Xq, const unsigned short* __restrict__ Xk,
              const unsigned short* __restrict__ Xv,
              const unsigned short* __restrict__ wq, const unsigned short* __restrict__ wk,
              const unsigned short* __restrict__ wv,
              const float* __restrict__ bq, const float* __restrict__ bk,
              const float* __restrict__ bv,
              unsigned short* __restrict__ qout, unsigned short* __restrict__ kout,
              unsigned short* __restrict__ vtout) {
  __shared__ char lds_raw[33280];
  const int z = blockIdx.z;
  const unsigned short* A  = z == 0 ? Xq : z == 1 ? Xk : Xv;
  const unsigned short* Bw = z == 0 ? wq : z == 1 ? wk : wv;
  const float* bias        = z == 0 ? bq : z == 1 ? bk : bv;

  unsigned short* Alds = (unsigned short*)lds_raw;
  unsigned short* Blds = (unsigned short*)(lds_raw + 16384);
  const int t = threadIdx.x;
  const int l = t & 63, w = t >> 6;
  const int lrow = l & 15, lk = l >> 4;
  const int rbase = blockIdx.y * 128, cbase = blockIdx.x * 128;
  const int wm = w >> 1, wn = w & 1;
  f32x4 acc[4][4] = {};

  for (int k0 = 0; k0 < 512; k0 += 64) {
    __syncthreads();
#pragma unroll
    for (int i = 0; i < 4; ++i) {
      int byteoff = w * 4096 + i * 1024;
      int row = w * 32 + i * 8 + (l >> 3);
      int chunk = l & 7;
      GLDS(A + (size_t)(rbase + row) * 512 + k0 + chunk * 8, lds_raw + byteoff);
      GLDS(Bw + (size_t)(cbase + row) * 512 + k0 + chunk * 8, lds_raw + 16384 + byteoff);
    }
    __syncthreads();
    bf16x8 af[4][2], bfr[4][2];
#pragma unroll
    for (int mt = 0; mt < 4; ++mt)
#pragma unroll
      for (int ks = 0; ks < 2; ++ks) {
        af[mt][ks]  = *reinterpret_cast<const bf16x8*>(Alds + (wm * 64 + mt * 16 + lrow) * 64 + ks * 32 + lk * 8);
        bfr[mt][ks] = *reinterpret_cast<const bf16x8*>(Blds + (wn * 64 + mt * 16 + lrow) * 64 + ks * 32 + lk * 8);
      }
#pragma unroll
    for (int mt = 0; mt < 4; ++mt)
#pragma unroll
      for (int nt = 0; nt < 4; ++nt) {
        acc[mt][nt] = __builtin_amdgcn_mfma_f32_16x16x32_bf16(af[mt][0], bfr[nt][0], acc[mt][nt], 0, 0, 0);
        acc[mt][nt] = __builtin_amdgcn_mfma_f32_16x16x32_bf16(af[mt][1], bfr[nt][1], acc[mt][nt], 0, 0, 0);
      }
  }

  float bvv[4];
#pragma unroll
  for (int nt = 0; nt < 4; ++nt) bvv[nt] = bias[cbase + wn * 64 + nt * 16 + lrow];

  if (z < 2) {
    unsigned short* out = z == 0 ? qout : kout;
#pragma unroll
    for (int mt = 0; mt < 4; ++mt)
#pragma unroll
      for (int nt = 0; nt < 4; ++nt)
#pragma unroll
        for (int r = 0; r < 4; ++r) {
          int rg = rbase + wm * 64 + mt * 16 + lk * 4 + r;
          int cg = cbase + wn * 64 + nt * 16 + lrow;
          out[(size_t)rg * 512 + cg] = f2bf(acc[mt][nt][r] + bvv[nt]);
        }
  } else {
    __syncthreads();
    unsigned short* tl = (unsigned short*)lds_raw;  // [128][130]
#pragma unroll
    for (int mt = 0; mt < 4; ++mt)
#pragma unroll
      for (int nt = 0; nt < 4; ++nt)
#pragma unroll
        for (int r = 0; r < 4; ++r)
          tl[(wm * 64 + mt * 16 + lk * 4 + r) * 130 + wn * 64 + nt * 16 + lrow] =
              f2bf(acc[mt][nt][r] + bvv[nt]);
    __syncthreads();
    const int bc = rbase >> 11;
    const int sb = rbase & 2047;
#pragma unroll
    for (int rnd = 0; rnd < 8; ++rnd) {
      int idx = rnd * 256 + t;
      int el = idx >> 4;
      int ch = idx & 15;
      u16x8 pk;
#pragma unroll
      for (int j2 = 0; j2 < 8; ++j2) pk[j2] = tl[(ch * 8 + j2) * 130 + el];
      int eg = cbase + el;
      int hh = eg >> 6, dd = eg & 63;
      *reinterpret_cast<u16x8*>(vtout + ((size_t)(bc * 8 + hh) * 64 + dd) * 2048 + sb + ch * 8) = pk;
    }
  }
}

// ---------------- output GEMM (fp32 out) ----------------
__global__ __launch_bounds__(256, 3)
void gemm_out(const unsigned short* __restrict__ A, const unsigned short* __restrict__ Bw,
              const float* __restrict__ bias, float* __restrict__ out) {
  __shared__ char lds_raw[32768];
  unsigned short* Alds = (unsigned short*)lds_raw;
  unsigned short* Blds = (unsigned short*)(lds_raw + 16384);
  const int t = threadIdx.x;
  const int l = t & 63, w = t >> 6;
  const int lrow = l & 15, lk = l >> 4;
  const int rbase = blockIdx.y * 128, cbase = blockIdx.x * 128;
  const int wm = w >> 1, wn = w & 1;
  f32x4 acc[4][4] = {};

  for (int k0 = 0; k0 < 512; k0 += 64) {
    __syncthreads();
#pragma unroll
    for (int i = 0; i < 4; ++i) {
      int byteoff = w * 4096 + i * 1024;
      int row = w * 32 + i * 8 + (l >> 3);
      int chunk = l & 7;
      GLDS(A + (size_t)(rbase + row) * 512 + k0 + chunk * 8, lds_raw + byteoff);
      GLDS(Bw + (size_t)(cbase + row) * 512 + k0 + chunk * 8, lds_raw + 16384 + byteoff);
    }
    __syncthreads();
    bf16x8 af[4][2], bfr[4][2];
#pragma unroll
    for (int mt = 0; mt < 4; ++mt)
#pragma unroll
      for (int ks = 0; ks < 2; ++ks) {
        af[mt][ks]  = *reinterpret_cast<const bf16x8*>(Alds + (wm * 64 + mt * 16 + lrow) * 64 + ks * 32 + lk * 8);
        bfr[mt][ks] = *reinterpret_cast<const bf16x8*>(Blds + (wn * 64 + mt * 16 + lrow) * 64 + ks * 32 + lk * 8);
      }
#pragma unroll
    for (int mt = 0; mt < 4; ++mt)
#pragma unroll
      for (int nt = 0; nt < 4; ++nt) {
        acc[mt][nt] = __builtin_amdgcn_mfma_f32_16x16x32_bf16(af[mt][0], bfr[nt][0], acc[mt][nt], 0, 0, 0);
        acc[mt][nt] = __builtin_amdgcn_mfma_f32_16x16x32_bf16(af[mt][1], bfr[nt][1], acc[mt][nt], 0, 0, 0);
      }
  }

  float bvv[4];
#pragma unroll
  for (int nt = 0; nt < 4; ++nt) bvv[nt] = bias[cbase + wn * 64 + nt * 16 + lrow];
#pragma unroll
  for (int mt = 0; mt < 4; ++mt)
#pragma unroll
    for (int nt = 0; nt < 4; ++nt)
#pragma unroll
      for (int r = 0; r < 4; ++r) {
        int rg = rbase + wm * 64 + mt * 16 + lk * 4 + r;
        int cg = cbase + wn * 64 + nt * 16 + lrow;
        out[(size_t)rg * 512 + cg] = acc[mt][nt][r] + bvv[nt];
      }
}

// ---------------- fused windowed attention (R3) ----------------
// 1024 wgs, 256 thr = 4 waves x 32 q. Swapped QK^T: sc = mfma(K,Q) ->
// D[row=key][col=query]; lane (g=l>>4, m=l&15) holds, for query q=qlo+rt*16+m,
// keys tt*64 + kt*16 + g*4 + r. Softmax with m==0 (bounded scores): row-sum is
// in-register + 2 shuffles at the END only. P packed via v_cvt_pk_bf16_f32 ->
// ds_write_b64 into per-wave 2KB buffer (32-key halves); PV: A=P, B=V(from V^T
// lds). Zero-pad handled analytically: ls += max(0,255-p).
__global__ __launch_bounds__(256, 4)
void attn_kernel(const unsigned short* __restrict__ qm, const unsigned short* __restrict__ km,
                 const unsigned short* __restrict__ vtm, unsigned short* __restrict__ ctx) {
  __shared__ char lds_raw[40960];  // 2 x (K 8KB | V^T 8KB) | P: 4 waves x 2KB
  const int t = threadIdx.x, l = t & 63, w = t >> 6;
  char* Pl = lds_raw + 32768 + w * 2048;
  const int lm = l & 15, g = l >> 4;

  int flat = blockIdx.x;
  int swz = (flat & 7) * 128 + (flat >> 3);   // nwg=1024, bijective XCD swizzle
  const int jh = swz & 15, h = (swz >> 4) & 7, bc = swz >> 7;

  const int Qb = jh * 128;
  const int qlo = Qb + w * 32;
  const int h64 = h * 64;
  const size_t bcrow = (size_t)bc * 2048;
  const size_t bch64 = ((size_t)(bc * 8 + h)) * 64;

  const int tlo = (Qb > 255 ? Qb - 255 : 0) >> 6;
  const int thi = (Qb + 127) >> 6;
  const int nt = thi - tlo + 1;                 // block tile count (2,4,6)
  const int wlo = (qlo > 255 ? qlo - 255 : 0) >> 6;
  const int whi = (qlo + 31) >> 6;

  auto stage = [&](int tt, int buf) {
    char* Kb = lds_raw + buf * 16384;
#pragma unroll
    for (int i = 0; i < 2; ++i) {
      int byteoff = w * 2048 + i * 1024;
      int row = w * 16 + i * 8 + (l >> 3);
      int clog = (l & 7) ^ (row & 7);            // pre-swizzled source (rule #21)
      GLDS(km + (bcrow + tt * 64 + row) * 512 + h64 + clog * 8, Kb + byteoff);
      GLDS(vtm + (bch64 + row) * 2048 + tt * 64 + clog * 8, Kb + 8192 + byteoff);
    }
  };

  // Q fragments (B-operand: lane holds Q[q=lm+rt*16][d=g*8+j+32ks])
  bf16x8 qf[2][2];
#pragma unroll
  for (int rt = 0; rt < 2; ++rt)
#pragma unroll
    for (int ks = 0; ks < 2; ++ks)
      qf[rt][ks] = *reinterpret_cast<const bf16x8*>(
          qm + (bcrow + qlo + rt * 16 + lm) * 512 + h64 + ks * 32 + g * 8);

  f32x4 oacc[2][4] = {};
  float ls[2] = {0.f, 0.f};

  stage(tlo, 0);
  __syncthreads();

  for (int it = 0; it < nt; ++it) {
    const int tt = tlo + it;
    if (it + 1 < nt) stage(tt + 1, (it + 1) & 1);

    if (tt >= wlo && tt <= whi) {
      char* Kb = lds_raw + (it & 1) * 16384;
      char* Vb = Kb + 8192;

      // QK^T swapped: sc[rt][kt] lane-holds keys (g*4+r), query (rt*16+lm)
      f32x4 sc[2][4];
      f32x4 zero = {};
#pragma unroll
      for (int kt = 0; kt < 4; ++kt) {
        int krow = kt * 16 + lm;
        const char* kbase = Kb + krow * 128;
        bf16x8 kf0 = *reinterpret_cast<const bf16x8*>(kbase + ((g ^ (krow & 7)) << 4));
        bf16x8 kf1 = *reinterpret_cast<const bf16x8*>(kbase + (((4 + g) ^ (krow & 7)) << 4));
#pragma unroll
        for (int rt = 0; rt < 2; ++rt) {
          f32x4 s0 = __builtin_amdgcn_mfma_f32_16x16x32_bf16(kf0, qf[rt][0], zero, 0, 0, 0);
          sc[rt][kt] = __builtin_amdgcn_mfma_f32_16x16x32_bf16(kf1, qf[rt][1], s0, 0, 0, 0);
        }
      }

      // softmax numerator (m == 0): P = exp(S/8); mask only on boundary tiles
      const bool interior = (tt * 64 + 63 <= qlo) && (tt * 64 >= qlo + 31 - 255);
      if (interior) {
#pragma unroll
        for (int rt = 0; rt < 2; ++rt) {
          float acc = 0.f;
#pragma unroll
          for (int kt = 0; kt < 4; ++kt)
#pragma unroll
            for (int r = 0; r < 4; ++r) {
              float pv = __expf(sc[rt][kt][r] * 0.125f);
              sc[rt][kt][r] = pv;
              acc += pv;
            }
          ls[rt] += acc;
        }
      } else {
#pragma unroll
        for (int rt = 0; rt < 2; ++rt) {
          int d0 = qlo + rt * 16 + lm - (tt * 64 + g * 4);  // q - key_base
          float acc = 0.f;
#pragma unroll
          for (int kt = 0; kt < 4; ++kt)
#pragma unroll
            for (int r = 0; r < 4; ++r) {
              bool ok = (unsigned)(d0 - (kt * 16 + r)) <= 255u;  // 0<=q-key<=255
              float pv = ok ? __expf(sc[rt][kt][r] * 0.125f) : 0.f;
              sc[rt][kt][r] = pv;
              acc += pv;
            }
          ls[rt] += acc;
        }
      }

      // PV in two 32-key halves: pack P -> LDS -> A-frag; B = V from V^T lds
#pragma unroll
      for (int ks = 0; ks < 2; ++ks) {
#pragma unroll
        for (int rt = 0; rt < 2; ++rt)
#pragma unroll
          for (int ktl = 0; ktl < 2; ++ktl) {
            int kt = ks * 2 + ktl;
            unsigned u0, u1;
            asm("v_cvt_pk_bf16_f32 %0, %1, %2" : "=v"(u0) : "v"(sc[rt][kt][0]), "v"(sc[rt][kt][1]));
            asm("v_cvt_pk_bf16_f32 %0, %1, %2" : "=v"(u1) : "v"(sc[rt][kt][2]), "v"(sc[rt][kt][3]));
            u32x2 uu; uu[0] = u0; uu[1] = u1;
            *reinterpret_cast<u32x2*>(Pl + (rt * 16 + lm) * 64 + ktl * 32 + g * 8) = uu;
          }
        bf16x8 pa[2];
        pa[0] = *reinterpret_cast<const bf16x8*>(Pl + lm * 64 + g * 16);
        pa[1] = *reinterpret_cast<const bf16x8*>(Pl + (16 + lm) * 64 + g * 16);
        bf16x8 vb[4];
#pragma unroll
        for (int dt = 0; dt < 4; ++dt) {
          int vrow = dt * 16 + lm;
          vb[dt] = *reinterpret_cast<const bf16x8*>(Vb + vrow * 128 + (((ks * 4 + g) ^ (vrow & 7)) << 4));
        }
#pragma unroll
        for (int rt = 0; rt < 2; ++rt)
#pragma unroll
          for (int dt = 0; dt < 4; ++dt)
            oacc[rt][dt] = __builtin_amdgcn_mfma_f32_16x16x32_bf16(pa[rt], vb[dt], oacc[rt][dt], 0, 0, 0);
      }
    }
    __syncthreads();
  }

  // finalize denominator: cross-group reduce + analytic zero-pad (exp(0)=1 each)
#pragma unroll
  for (int rt = 0; rt < 2; ++rt) {
    ls[rt] += __shfl_xor(ls[rt], 16, 64);
    ls[rt] += __shfl_xor(ls[rt], 32, 64);
    int cp = 255 - (qlo + rt * 16 + lm);
    if (cp > 0) ls[rt] += (float)cp;
  }

  // redistribute 1/ls from softmax layout (q=lm) to oacc layout (q=g*4+r) via LDS
  float* Pf = (float*)Pl;
  Pf[lm] = 1.f / ls[0];
  Pf[16 + lm] = 1.f / ls[1];
  float inv0[2][4];
#pragma unroll
  for (int rt = 0; rt < 2; ++rt)
#pragma unroll
    for (int r = 0; r < 4; ++r)
      inv0[rt][r] = Pf[rt * 16 + g * 4 + r];

  // store ctx bf16 [b,c,s,h*64+d]; oacc: row q = rt*16+g*4+r, col d = dt*16+lm
#pragma unroll
  for (int rt = 0; rt < 2; ++rt)
#pragma unroll
    for (int dt = 0; dt < 4; ++dt)
#pragma unroll
      for (int r = 0; r < 4; ++r) {
        size_t rg = bcrow + qlo + rt * 16 + g * 4 + r;
        int cg = h64 + dt * 16 + lm;
        ctx[rg * 512 + cg] = f2bf(oacc[rt][dt][r] * inv0[rt][r]);
      }
}

// ---------------- launch ----------------
extern "C" void kernel_launch(void* const* d_in, const int* in_sizes, int n_in,
                              void* d_out, int out_size, void* d_ws, size_t ws_size,
                              hipStream_t stream) {
  const float* q_in = (const float*)d_in[0];
  const float* k_in = (const float*)d_in[1];
  const float* v_in = (const float*)d_in[2];
  const float* Wq = (const float*)d_in[3];
  const float* bq = (const float*)d_in[4];
  const float* Wk = (const float*)d_in[5];
  const float* bk = (const float*)d_in[6];
  const float* Wv = (const float*)d_in[7];
  const float* bv = (const float*)d_in[8];
  const float* Wo = (const float*)d_in[9];
  const float* bo = (const float*)d_in[10];

  char* ws = (char*)d_ws;
  const size_t SZ = (size_t)16384 * 512 * 2;
  unsigned short* Xq = (unsigned short*)(ws);
  unsigned short* Xk = (unsigned short*)(ws + SZ);
  unsigned short* Xv = (unsigned short*)(ws + 2 * SZ);
  unsigned short* qb = (unsigned short*)(ws + 3 * SZ);
  unsigned short* kb = (unsigned short*)(ws + 4 * SZ);
  unsigned short* wq_b = (unsigned short*)(ws + 5 * SZ);
  unsigned short* wk_b = wq_b + 262144;
  unsigned short* wv_b = wk_b + 262144;
  unsigned short* wo_b = wv_b + 262144;
  unsigned short* vtb = (unsigned short*)d_out;  // vT in d_out (dead before gemm_out)
  unsigned short* ctx = Xq;                      // Xq dead after q-GEMM

  convert_all<<<dim3(4096, 1, 4), 256, 0, stream>>>(q_in, k_in, v_in, Wq, Wk, Wv, Wo,
                                                    Xq, Xk, Xv, wq_b, wk_b, wv_b, wo_b);
  gemm_qkv<<<dim3(4, 128, 3), 256, 0, stream>>>(Xq, Xk, Xv, wq_b, wk_b, wv_b,
                                                bq, bk, bv, qb, kb, vtb);
  attn_kernel<<<1024, 256, 0, stream>>>(qb, kb, vtb, ctx);
  gemm_out<<<dim3(4, 128), 256, 0, stream>>>(ctx, wo_b, bo, (float*)d_out);
}